// Round 1
// baseline (173.363 us; speedup 1.0000x reference)
//
#include <hip/hip_runtime.h>
#include <hip/hip_bf16.h>
#include <cstdint>
#include <cstddef>

#define BATCH 16
#define NROWS 4096
#define MROWS 2048
#define DDIM  256
#define NSPLIT 4
#define MTILE 128   // m columns per block
#define NTILE 128   // n rows per chunk
#define BK    64

typedef __attribute__((ext_vector_type(8))) short short8;
typedef __attribute__((ext_vector_type(4))) float f32x4;

static __device__ __forceinline__ unsigned short f2bf(float f) {
  unsigned int x = __float_as_uint(f);
  x += 0x7fffu + ((x >> 16) & 1u);
  return (unsigned short)(x >> 16);
}

// ---------------- Kernel 1: row L2-normalize + bf16 cast ----------------
__global__ void __launch_bounds__(256) norm_cast(
    const float* __restrict__ x1, const float* __restrict__ x2,
    unsigned short* __restrict__ aout, unsigned short* __restrict__ bout) {
  const int wid  = threadIdx.x >> 6;
  const int lane = threadIdx.x & 63;
  const long long row = (long long)blockIdx.x * 4 + wid;
  const long long R1 = (long long)BATCH * NROWS;
  const long long R2 = (long long)BATCH * MROWS;
  if (row >= R1 + R2) return;
  const float* src; unsigned short* dst;
  if (row < R1) { src = x1 + row * DDIM; dst = aout + row * DDIM; }
  else { long long r2 = row - R1; src = x2 + r2 * DDIM; dst = bout + r2 * DDIM; }
  float4 v = ((const float4*)src)[lane];
  float ss = v.x*v.x + v.y*v.y + v.z*v.z + v.w*v.w;
  #pragma unroll
  for (int o = 32; o >= 1; o >>= 1) ss += __shfl_xor(ss, o, 64);
  float n = sqrtf(ss);
  float sc = 1.0f / fmaxf(n, 1e-12f);
  ushort4 o;
  o.x = f2bf(v.x * sc); o.y = f2bf(v.y * sc);
  o.z = f2bf(v.z * sc); o.w = f2bf(v.w * sc);
  ((ushort4*)dst)[lane] = o;
}

// ---------------- Kernel 2: fused GEMM + column-max ----------------
// C[n][m] = a_hat[n]·b_hat[m]; running max over n per column m.
typedef __attribute__((address_space(1))) const void gas_t;
typedef __attribute__((address_space(3))) void las_t;
#define GLL16(g, l) __builtin_amdgcn_global_load_lds((gas_t*)(g), (las_t*)(l), 16, 0, 0)

__global__ void __launch_bounds__(256) maxsim_gemm(
    const unsigned short* __restrict__ A,   // [BATCH][NROWS][DDIM] bf16
    const unsigned short* __restrict__ Bm,  // [BATCH][MROWS][DDIM] bf16
    float* __restrict__ partials)           // [NSPLIT][BATCH][MROWS]
{
  __shared__ __align__(16) unsigned short As[NTILE * BK];
  __shared__ __align__(16) unsigned short Bs[MTILE * BK];
  __shared__ float cmax_s[2][MTILE];

  const int t    = threadIdx.x;
  const int lane = t & 63;
  const int w    = t >> 6;
  const int wr   = w >> 1;   // n-half of the 128x128 tile
  const int wc   = w & 1;    // m-half

  int bid = blockIdx.x;
  const int sp = bid & (NSPLIT - 1); bid >>= 2;
  const int mt = bid & 15;           bid >>= 4;
  const int bb = bid;

  const int m0    = mt * MTILE;
  const int nbase = sp * (NROWS / NSPLIT);

  const unsigned short* Abase = A  + (size_t)bb * NROWS * DDIM;
  const unsigned short* Bbase = Bm + ((size_t)bb * MROWS + m0) * DDIM;

  const int srow = t >> 3;        // staging row 0..31 (per issue)
  const int scol = (t & 7) * 8;   // staging col (elements)
  char* lA = (char*)As + t * 16;
  char* lB = (char*)Bs + t * 16;

  const int lrow = lane & 15;
  const int lk   = (lane >> 4) * 8;

  float cm[4];
  #pragma unroll
  for (int j = 0; j < 4; ++j) cm[j] = -INFINITY;

  for (int nc = 0; nc < (NROWS / NSPLIT) / NTILE; ++nc) {
    const int n0 = nbase + nc * NTILE;
    f32x4 acc[4][4] = {};

    for (int k0 = 0; k0 < DDIM; k0 += BK) {
      const unsigned short* ga = Abase + ((size_t)(n0 + srow) * DDIM + k0 + scol);
      const unsigned short* gb = Bbase + ((size_t)srow * DDIM + k0 + scol);
      #pragma unroll
      for (int i = 0; i < 4; ++i) {
        GLL16(ga + (size_t)i * 32 * DDIM, lA + i * 4096);
        GLL16(gb + (size_t)i * 32 * DDIM, lB + i * 4096);
      }
      __syncthreads();
      #pragma unroll
      for (int ks = 0; ks < 2; ++ks) {
        short8 af[4], bfr[4];
        #pragma unroll
        for (int i = 0; i < 4; ++i)
          af[i] = *(const short8*)&As[(wr*64 + i*16 + lrow) * BK + ks*32 + lk];
        #pragma unroll
        for (int j = 0; j < 4; ++j)
          bfr[j] = *(const short8*)&Bs[(wc*64 + j*16 + lrow) * BK + ks*32 + lk];
        #pragma unroll
        for (int i = 0; i < 4; ++i)
          #pragma unroll
          for (int j = 0; j < 4; ++j)
            acc[i][j] = __builtin_amdgcn_mfma_f32_16x16x32_bf16(af[i], bfr[j], acc[i][j], 0, 0, 0);
      }
      __syncthreads();
    }
    // fold this chunk's C tile into the running column max
    #pragma unroll
    for (int j = 0; j < 4; ++j) {
      float v = cm[j];
      #pragma unroll
      for (int i = 0; i < 4; ++i) {
        v = fmaxf(v, acc[i][j][0]);
        v = fmaxf(v, acc[i][j][1]);
        v = fmaxf(v, acc[i][j][2]);
        v = fmaxf(v, acc[i][j][3]);
      }
      cm[j] = v;
    }
  }

  // reduce across the 4 lane-groups holding the same column (lane&15)
  #pragma unroll
  for (int j = 0; j < 4; ++j) {
    cm[j] = fmaxf(cm[j], __shfl_xor(cm[j], 16, 64));
    cm[j] = fmaxf(cm[j], __shfl_xor(cm[j], 32, 64));
  }
  if (lane < 16) {
    #pragma unroll
    for (int j = 0; j < 4; ++j) cmax_s[wr][wc*64 + j*16 + lane] = cm[j];
  }
  __syncthreads();
  if (t < MTILE) {
    float v = fmaxf(cmax_s[0][t], cmax_s[1][t]);
    partials[((size_t)sp * BATCH + bb) * MROWS + m0 + t] = v;
  }
}

// ---------------- Kernel 3: combine partial maxes -> loss ----------------
__global__ void __launch_bounds__(256) finalize_loss(
    const float* __restrict__ partials, const float* __restrict__ y,
    float* __restrict__ out) {
  __shared__ float red[256];
  const int t = threadIdx.x;
  float total = 0.0f;
  for (int b = 0; b < BATCH; ++b) {
    float s = 0.0f;
    for (int m = t; m < MROWS; m += 256) {
      float v = partials[(size_t)b * MROWS + m];
      #pragma unroll
      for (int sp = 1; sp < NSPLIT; ++sp)
        v = fmaxf(v, partials[((size_t)sp * BATCH + b) * MROWS + m]);
      s += v;
    }
    red[t] = s;
    __syncthreads();
    for (int o = 128; o >= 1; o >>= 1) {
      if (t < o) red[t] += red[t + o];
      __syncthreads();
    }
    if (t == 0) {
      float mean = red[0] / (float)MROWS;
      float yb = y[b];
      float d = mean - yb;
      float scale = (yb != 0.0f) ? 1.0f : 1.0f;  // Y_SCALE == 1.0
      total += d * d * scale;
    }
    __syncthreads();
  }
  if (t == 0) out[0] = total;
}

extern "C" void kernel_launch(void* const* d_in, const int* in_sizes, int n_in,
                              void* d_out, int out_size, void* d_ws, size_t ws_size,
                              hipStream_t stream) {
  const float* x1 = (const float*)d_in[0];
  const float* x2 = (const float*)d_in[1];
  const float* y  = (const float*)d_in[2];
  float* out = (float*)d_out;

  unsigned short* aBF = (unsigned short*)d_ws;                       // 32 MB
  unsigned short* bBF = aBF + (size_t)BATCH * NROWS * DDIM;          // 16 MB
  float* partials = (float*)(bBF + (size_t)BATCH * MROWS * DDIM);    // 512 KB

  const int totRows = BATCH * (NROWS + MROWS);
  norm_cast<<<(totRows + 3) / 4, 256, 0, stream>>>(x1, x2, aBF, bBF);
  maxsim_gemm<<<BATCH * 16 * NSPLIT, 256, 0, stream>>>(aBF, bBF, partials);
  finalize_loss<<<1, 256, 0, stream>>>(partials, y, out);
}

// Round 2
// 101.958 us; speedup vs baseline: 1.7003x; 1.7003x over previous
//
#include <hip/hip_runtime.h>
#include <hip/hip_bf16.h>
#include <cstdint>
#include <cstddef>

#define BATCH 16
#define NROWS 4096
#define MROWS 2048
#define DDIM  256
#define NSPLIT 4
#define MTILE 128   // m columns per block
#define NTILE 128   // n rows per chunk
#define BK    64

typedef __attribute__((ext_vector_type(8))) short short8;
typedef __attribute__((ext_vector_type(4))) float f32x4;

static __device__ __forceinline__ unsigned short f2bf(float f) {
  unsigned int x = __float_as_uint(f);
  x += 0x7fffu + ((x >> 16) & 1u);
  return (unsigned short)(x >> 16);
}

// ---------------- Kernel 1: row L2-normalize + bf16 cast ----------------
__global__ void __launch_bounds__(256) norm_cast(
    const float* __restrict__ x1, const float* __restrict__ x2,
    unsigned short* __restrict__ aout, unsigned short* __restrict__ bout) {
  const int wid  = threadIdx.x >> 6;
  const int lane = threadIdx.x & 63;
  const long long row = (long long)blockIdx.x * 4 + wid;
  const long long R1 = (long long)BATCH * NROWS;
  const long long R2 = (long long)BATCH * MROWS;
  if (row >= R1 + R2) return;
  const float* src; unsigned short* dst;
  if (row < R1) { src = x1 + row * DDIM; dst = aout + row * DDIM; }
  else { long long r2 = row - R1; src = x2 + r2 * DDIM; dst = bout + r2 * DDIM; }
  float4 v = ((const float4*)src)[lane];
  float ss = v.x*v.x + v.y*v.y + v.z*v.z + v.w*v.w;
  #pragma unroll
  for (int o = 32; o >= 1; o >>= 1) ss += __shfl_xor(ss, o, 64);
  float n = sqrtf(ss);
  float sc = 1.0f / fmaxf(n, 1e-12f);
  ushort4 o;
  o.x = f2bf(v.x * sc); o.y = f2bf(v.y * sc);
  o.z = f2bf(v.z * sc); o.w = f2bf(v.w * sc);
  ((ushort4*)dst)[lane] = o;
}

// ---------------- Kernel 2: fused GEMM + column-max ----------------
// C[n][m] = a_hat[n]·b_hat[m]; running max over n per column m.
typedef __attribute__((address_space(1))) const void gas_t;
typedef __attribute__((address_space(3))) void las_t;
#define GLL16(g, l) __builtin_amdgcn_global_load_lds((gas_t*)(g), (las_t*)(l), 16, 0, 0)

__global__ void __launch_bounds__(256, 4) maxsim_gemm(
    const unsigned short* __restrict__ A,   // [BATCH][NROWS][DDIM] bf16
    const unsigned short* __restrict__ Bm,  // [BATCH][MROWS][DDIM] bf16
    float* __restrict__ partials)           // [NSPLIT][BATCH][MROWS]
{
  __shared__ __align__(16) unsigned short As[NTILE * BK];
  __shared__ __align__(16) unsigned short Bs[MTILE * BK];
  __shared__ float cmax_s[2][MTILE];

  const int t    = threadIdx.x;
  const int lane = t & 63;
  const int w    = t >> 6;
  const int wr   = w >> 1;   // n-half of the 128x128 tile
  const int wc   = w & 1;    // m-half

  // XCD-aware swizzle: hw blockIdx round-robins XCDs (hw%8). Remap so XCD k
  // owns logical ids [128k,128k+128) = batches {2k,2k+1} complete:
  // all 4 sp * 16 mt blocks of a batch share one L2 -> A panel and B tiles
  // are served from L2 after the compulsory fill.
  const int hw = blockIdx.x;                       // 1024 blocks
  const int logical = (hw & 7) * 128 + (hw >> 3);  // bijective
  const int mt  = logical & 15;
  const int grp = logical >> 4;    // 0..63
  const int sp  = grp & 3;
  const int bb  = grp >> 2;

  const int m0    = mt * MTILE;
  const int nbase = sp * (NROWS / NSPLIT);

  const unsigned short* Abase = A  + (size_t)bb * NROWS * DDIM;
  const unsigned short* Bbase = Bm + ((size_t)bb * MROWS + m0) * DDIM;

  const int srow = t >> 3;        // staging row 0..31 (per issue)
  const int scol = (t & 7) * 8;   // staging col (elements)
  char* lA = (char*)As + t * 16;
  char* lB = (char*)Bs + t * 16;

  const int lrow = lane & 15;
  const int lk   = (lane >> 4) * 8;

  float cm[4];
  #pragma unroll
  for (int j = 0; j < 4; ++j) cm[j] = -INFINITY;

  for (int nc = 0; nc < (NROWS / NSPLIT) / NTILE; ++nc) {
    const int n0 = nbase + nc * NTILE;
    f32x4 acc[4][4] = {};

    for (int k0 = 0; k0 < DDIM; k0 += BK) {
      const unsigned short* ga = Abase + ((size_t)(n0 + srow) * DDIM + k0 + scol);
      const unsigned short* gb = Bbase + ((size_t)srow * DDIM + k0 + scol);
      #pragma unroll
      for (int i = 0; i < 4; ++i) {
        GLL16(ga + (size_t)i * 32 * DDIM, lA + i * 4096);
        GLL16(gb + (size_t)i * 32 * DDIM, lB + i * 4096);
      }
      __syncthreads();
      #pragma unroll
      for (int ks = 0; ks < 2; ++ks) {
        short8 af[4], bfr[4];
        #pragma unroll
        for (int i = 0; i < 4; ++i)
          af[i] = *(const short8*)&As[(wr*64 + i*16 + lrow) * BK + ks*32 + lk];
        #pragma unroll
        for (int j = 0; j < 4; ++j)
          bfr[j] = *(const short8*)&Bs[(wc*64 + j*16 + lrow) * BK + ks*32 + lk];
        #pragma unroll
        for (int i = 0; i < 4; ++i)
          #pragma unroll
          for (int j = 0; j < 4; ++j)
            acc[i][j] = __builtin_amdgcn_mfma_f32_16x16x32_bf16(af[i], bfr[j], acc[i][j], 0, 0, 0);
      }
      __syncthreads();
    }
    // fold this chunk's C tile into the running column max
    #pragma unroll
    for (int j = 0; j < 4; ++j) {
      float v = cm[j];
      #pragma unroll
      for (int i = 0; i < 4; ++i) {
        v = fmaxf(v, acc[i][j][0]);
        v = fmaxf(v, acc[i][j][1]);
        v = fmaxf(v, acc[i][j][2]);
        v = fmaxf(v, acc[i][j][3]);
      }
      cm[j] = v;
    }
  }

  // reduce across the 4 lane-groups holding the same column (lane&15)
  #pragma unroll
  for (int j = 0; j < 4; ++j) {
    cm[j] = fmaxf(cm[j], __shfl_xor(cm[j], 16, 64));
    cm[j] = fmaxf(cm[j], __shfl_xor(cm[j], 32, 64));
  }
  if (lane < 16) {
    #pragma unroll
    for (int j = 0; j < 4; ++j) cmax_s[wr][wc*64 + j*16 + lane] = cm[j];
  }
  __syncthreads();
  if (t < MTILE) {
    float v = fmaxf(cmax_s[0][t], cmax_s[1][t]);
    partials[((size_t)sp * BATCH + bb) * MROWS + m0 + t] = v;
  }
}

// ---------------- Kernel 3a: per-batch loss ----------------
__global__ void __launch_bounds__(256) batch_loss(
    const float* __restrict__ partials, const float* __restrict__ y,
    float* __restrict__ bloss) {
  __shared__ float red[4];
  const int b = blockIdx.x;
  const int t = threadIdx.x;
  const int lane = t & 63;
  const int w = t >> 6;
  float s = 0.0f;
  for (int m = t; m < MROWS; m += 256) {
    float v = partials[(size_t)b * MROWS + m];
    #pragma unroll
    for (int sp = 1; sp < NSPLIT; ++sp)
      v = fmaxf(v, partials[((size_t)sp * BATCH + b) * MROWS + m]);
    s += v;
  }
  #pragma unroll
  for (int o = 32; o >= 1; o >>= 1) s += __shfl_xor(s, o, 64);
  if (lane == 0) red[w] = s;
  __syncthreads();
  if (t == 0) {
    float sum = red[0] + red[1] + red[2] + red[3];
    float mean = sum / (float)MROWS;
    float yb = y[b];
    float d = mean - yb;
    // Y_SCALE == 1.0 -> scale is 1 either way
    bloss[b] = d * d;
  }
}

// ---------------- Kernel 3b: combine per-batch losses ----------------
__global__ void __launch_bounds__(64) final_sum(
    const float* __restrict__ bloss, float* __restrict__ out) {
  const int t = threadIdx.x;
  float v = (t < BATCH) ? bloss[t] : 0.0f;
  #pragma unroll
  for (int o = 32; o >= 1; o >>= 1) v += __shfl_xor(v, o, 64);
  if (t == 0) out[0] = v;
}

extern "C" void kernel_launch(void* const* d_in, const int* in_sizes, int n_in,
                              void* d_out, int out_size, void* d_ws, size_t ws_size,
                              hipStream_t stream) {
  const float* x1 = (const float*)d_in[0];
  const float* x2 = (const float*)d_in[1];
  const float* y  = (const float*)d_in[2];
  float* out = (float*)d_out;

  unsigned short* aBF = (unsigned short*)d_ws;                       // 32 MB
  unsigned short* bBF = aBF + (size_t)BATCH * NROWS * DDIM;          // 16 MB
  float* partials = (float*)(bBF + (size_t)BATCH * MROWS * DDIM);    // 512 KB
  float* bloss = partials + (size_t)NSPLIT * BATCH * MROWS;          // 64 B

  const int totRows = BATCH * (NROWS + MROWS);
  norm_cast<<<(totRows + 3) / 4, 256, 0, stream>>>(x1, x2, aBF, bBF);
  maxsim_gemm<<<BATCH * 16 * NSPLIT, 256, 0, stream>>>(aBF, bBF, partials);
  batch_loss<<<BATCH, 256, 0, stream>>>(partials, y, bloss);
  final_sum<<<1, 64, 0, stream>>>(bloss, out);
}

// Round 3
// 85.857 us; speedup vs baseline: 2.0192x; 1.1875x over previous
//
#include <hip/hip_runtime.h>
#include <hip/hip_bf16.h>
#include <cstdint>
#include <cstddef>

#define BATCH 16
#define NROWS 4096
#define MROWS 2048
#define DDIM  256
#define NSPLIT 2
#define NCHUNKS 8            // (NROWS/NSPLIT)/256

typedef __attribute__((ext_vector_type(8))) short short8;
typedef __attribute__((ext_vector_type(4))) float f32x4;

static __device__ __forceinline__ unsigned short f2bf(float f) {
  unsigned int x = __float_as_uint(f);
  x += 0x7fffu + ((x >> 16) & 1u);
  return (unsigned short)(x >> 16);
}

// ---------------- Kernel 1: row L2-normalize + bf16 cast ----------------
__global__ void __launch_bounds__(256) norm_cast(
    const float* __restrict__ x1, const float* __restrict__ x2,
    unsigned short* __restrict__ aout, unsigned short* __restrict__ bout) {
  const int wid  = threadIdx.x >> 6;
  const int lane = threadIdx.x & 63;
  const long long row = (long long)blockIdx.x * 4 + wid;
  const long long R1 = (long long)BATCH * NROWS;
  const long long R2 = (long long)BATCH * MROWS;
  if (row >= R1 + R2) return;
  const float* src; unsigned short* dst;
  if (row < R1) { src = x1 + row * DDIM; dst = aout + row * DDIM; }
  else { long long r2 = row - R1; src = x2 + r2 * DDIM; dst = bout + r2 * DDIM; }
  float4 v = ((const float4*)src)[lane];
  float ss = v.x*v.x + v.y*v.y + v.z*v.z + v.w*v.w;
  #pragma unroll
  for (int o = 32; o >= 1; o >>= 1) ss += __shfl_xor(ss, o, 64);
  float n = sqrtf(ss);
  float sc = 1.0f / fmaxf(n, 1e-12f);
  ushort4 o;
  o.x = f2bf(v.x * sc); o.y = f2bf(v.y * sc);
  o.z = f2bf(v.z * sc); o.w = f2bf(v.w * sc);
  ((ushort4*)dst)[lane] = o;
}

// ---------------- Kernel 2: 8-phase 256x256 fused GEMM + column-max ----------------
typedef __attribute__((address_space(1))) const void gas_t;
typedef __attribute__((address_space(3))) void las_t;
#define GLL16(g, l) __builtin_amdgcn_global_load_lds((gas_t*)(g), (las_t*)(l), 16, 0, 0)

// LDS: A halves [parity][ks] then B halves. Each slot: [256 rows][32 k] bf16 = 16 KB.
#define LDSA(P,K) (lds + (((P)*2+(K))<<14))
#define LDSB(P,K) (lds + 65536 + (((P)*2+(K))<<14))

// Stage one half-slot: rows [row0,row0+256) x k-cols [koff,koff+32) of `base`.
// LDS dest linear; source k-slot pre-swizzled: sphys = s ^ ((r>>1)&3).
static __device__ __forceinline__ void stage_half(
    const unsigned short* __restrict__ base, int row0, int koff,
    char* slot, int w, int lane) {
  #pragma unroll
  for (int i = 0; i < 2; ++i) {
    const int chunk = w * 2 + i;
    const int r = chunk * 16 + (lane >> 2);
    const int sphys = (lane & 3) ^ ((lane >> 3) & 3);
    const unsigned short* src = base + (size_t)(row0 + r) * DDIM + koff + (sphys << 3);
    GLL16(src, slot + chunk * 1024 + lane * 16);
  }
}

static __device__ __forceinline__ short8 ldsfrag(const char* slot, int row, int pslot) {
  return *(const short8*)(slot + row * 64 + (pslot << 4));
}

__global__ void __launch_bounds__(512, 2) maxsim_gemm8(
    const unsigned short* __restrict__ A,   // [BATCH][NROWS][DDIM]
    const unsigned short* __restrict__ Bm,  // [BATCH][MROWS][DDIM]
    float* __restrict__ partials)           // [NSPLIT][BATCH][MROWS]
{
  __shared__ __align__(16) char lds[131072];

  const int t = threadIdx.x;
  const int lane = t & 63;
  const int w = t >> 6;
  const int wr = w >> 2;     // n-half of 256 rows (wave owns 128)
  const int wc = w & 3;      // m-quarter (wave owns 64 cols)
  const int lrow = lane & 15;
  const int pslot = (lane >> 4) ^ ((lane >> 1) & 3);  // swizzled 16B slot for frag reads

  // XCD-aware bijective swizzle: 256 blocks, XCD k owns batches {2k,2k+1}.
  const int hw = blockIdx.x;
  const int logical = (hw & 7) * 32 + (hw >> 3);
  const int mt = logical & 7;
  const int grp = logical >> 3;
  const int sp = grp & 1;
  const int bb = grp >> 1;

  const int m0 = mt * 256;
  const int nbase = sp * (NROWS / NSPLIT);

  const unsigned short* Aba = A  + (size_t)bb * NROWS * DDIM;
  const unsigned short* Bba = Bm + ((size_t)bb * MROWS + m0) * DDIM;

  f32x4 acc[8][4] = {};
  short8 af[8];
  float cm[4] = {-INFINITY, -INFINITY, -INFINITY, -INFINITY};

  // ---- Prologue: stage tile0 (4 halves) + tile1 (A0,B0,A1) = 7 halves (14 loads/wave)
  stage_half(Aba, nbase, 0,  LDSA(0,0), w, lane);
  stage_half(Bba, 0,     0,  LDSB(0,0), w, lane);
  stage_half(Aba, nbase, 32, LDSA(0,1), w, lane);
  stage_half(Bba, 0,     32, LDSB(0,1), w, lane);
  stage_half(Aba, nbase, 64, LDSA(1,0), w, lane);
  stage_half(Bba, 0,     64, LDSB(1,0), w, lane);
  stage_half(Aba, nbase, 96, LDSA(1,1), w, lane);
  asm volatile("s_waitcnt vmcnt(6)" ::: "memory");   // tile0 fully landed
  asm volatile("s_barrier" ::: "memory");

  // Phase body: compute (ks,qj) quadrant of current tile; stage one half; counted vmcnt.
  #define PHASE(PAR, KS, QJ, LOADA, STAGE_STMT, VMW) do {                          \
    if (LOADA) {                                                                   \
      _Pragma("unroll")                                                            \
      for (int mi = 0; mi < 8; ++mi)                                               \
        af[mi] = ldsfrag(LDSA(PAR,KS), wr*128 + mi*16 + lrow, pslot);              \
    }                                                                              \
    short8 b0 = ldsfrag(LDSB(PAR,KS), wc*64 + (QJ)*32 + lrow, pslot);              \
    short8 b1 = ldsfrag(LDSB(PAR,KS), wc*64 + (QJ)*32 + 16 + lrow, pslot);         \
    STAGE_STMT;                                                                    \
    if (VMW) asm volatile("s_waitcnt vmcnt(6)" ::: "memory");                      \
    asm volatile("s_barrier" ::: "memory");                                        \
    __builtin_amdgcn_s_setprio(1);                                                 \
    _Pragma("unroll")                                                              \
    for (int mi = 0; mi < 8; ++mi) {                                               \
      acc[mi][(QJ)*2+0] = __builtin_amdgcn_mfma_f32_16x16x32_bf16(af[mi], b0, acc[mi][(QJ)*2+0], 0,0,0); \
      acc[mi][(QJ)*2+1] = __builtin_amdgcn_mfma_f32_16x16x32_bf16(af[mi], b1, acc[mi][(QJ)*2+1], 0,0,0); \
    }                                                                              \
    __builtin_amdgcn_s_setprio(0);                                                 \
    asm volatile("s_barrier" ::: "memory");                                        \
  } while (0)

  for (int nc = 0; nc < NCHUNKS; ++nc) {
    #pragma unroll
    for (int kt = 0; kt < 4; ++kt) {
      const int parity = kt & 1;
      // stage targets (ledger: ph0 -> tile T+1 B-ks1; ph1..3 -> tile T+2 A0,B0,A1)
      const int kt_s1 = (kt + 1) & 3;            // tile T+1 k-index
      const int kt_s2 = (kt + 2) & 3;            // tile T+2 k-index
      const int par1 = (kt + 1) & 1;
      const int par2 = kt & 1;
      const int nc_s2 = (kt < 2) ? nc : ((nc + 1) & (NCHUNKS - 1));  // wrap: junk-stage, never read
      const int arow2 = nbase + nc_s2 * 256;

      PHASE(parity, 0, 0, 1,
            stage_half(Bba, 0, kt_s1*64 + 32, LDSB(par1,1), w, lane), 0);
      PHASE(parity, 0, 1, 0,
            stage_half(Aba, arow2, kt_s2*64, LDSA(par2,0), w, lane), 0);
      PHASE(parity, 1, 0, 1,
            stage_half(Bba, 0, kt_s2*64, LDSB(par2,0), w, lane), 0);
      PHASE(parity, 1, 1, 0,
            stage_half(Aba, arow2, kt_s2*64 + 32, LDSA(par2,1), w, lane), 1);
    }
    // fold this n-chunk's C tile into running column max; reset acc
    #pragma unroll
    for (int nj = 0; nj < 4; ++nj) {
      float v = cm[nj];
      #pragma unroll
      for (int mi = 0; mi < 8; ++mi) {
        v = fmaxf(v, acc[mi][nj][0]);
        v = fmaxf(v, acc[mi][nj][1]);
        v = fmaxf(v, acc[mi][nj][2]);
        v = fmaxf(v, acc[mi][nj][3]);
        acc[mi][nj] = (f32x4){0.0f, 0.0f, 0.0f, 0.0f};
      }
      cm[nj] = v;
    }
  }
  #undef PHASE

  // ---- Epilogue: drain DMA, reduce max across lanes/waves, write partials
  asm volatile("s_waitcnt vmcnt(0)" ::: "memory");
  asm volatile("s_barrier" ::: "memory");
  float* cmax = (float*)lds;   // [2][256]
  #pragma unroll
  for (int nj = 0; nj < 4; ++nj) {
    cm[nj] = fmaxf(cm[nj], __shfl_xor(cm[nj], 16, 64));
    cm[nj] = fmaxf(cm[nj], __shfl_xor(cm[nj], 32, 64));
  }
  if (lane < 16) {
    #pragma unroll
    for (int nj = 0; nj < 4; ++nj)
      cmax[wr * 256 + wc * 64 + nj * 16 + lane] = cm[nj];
  }
  __syncthreads();
  if (t < 256) {
    float v = fmaxf(cmax[t], cmax[256 + t]);
    partials[((size_t)sp * BATCH + bb) * MROWS + m0 + t] = v;
  }
}

// ---------------- Kernel 3a: per-batch loss ----------------
__global__ void __launch_bounds__(256) batch_loss(
    const float* __restrict__ partials, const float* __restrict__ y,
    float* __restrict__ bloss) {
  __shared__ float red[4];
  const int b = blockIdx.x;
  const int t = threadIdx.x;
  const int lane = t & 63;
  const int w = t >> 6;
  float s = 0.0f;
  for (int m = t; m < MROWS; m += 256) {
    float v = partials[(size_t)b * MROWS + m];
    #pragma unroll
    for (int sp = 1; sp < NSPLIT; ++sp)
      v = fmaxf(v, partials[((size_t)sp * BATCH + b) * MROWS + m]);
    s += v;
  }
  #pragma unroll
  for (int o = 32; o >= 1; o >>= 1) s += __shfl_xor(s, o, 64);
  if (lane == 0) red[w] = s;
  __syncthreads();
  if (t == 0) {
    float sum = red[0] + red[1] + red[2] + red[3];
    float mean = sum / (float)MROWS;
    float yb = y[b];
    float d = mean - yb;
    bloss[b] = d * d;   // Y_SCALE == 1.0
  }
}

// ---------------- Kernel 3b: combine per-batch losses ----------------
__global__ void __launch_bounds__(64) final_sum(
    const float* __restrict__ bloss, float* __restrict__ out) {
  const int t = threadIdx.x;
  float v = (t < BATCH) ? bloss[t] : 0.0f;
  #pragma unroll
  for (int o = 32; o >= 1; o >>= 1) v += __shfl_xor(v, o, 64);
  if (t == 0) out[0] = v;
}

extern "C" void kernel_launch(void* const* d_in, const int* in_sizes, int n_in,
                              void* d_out, int out_size, void* d_ws, size_t ws_size,
                              hipStream_t stream) {
  const float* x1 = (const float*)d_in[0];
  const float* x2 = (const float*)d_in[1];
  const float* y  = (const float*)d_in[2];
  float* out = (float*)d_out;

  unsigned short* aBF = (unsigned short*)d_ws;
  unsigned short* bBF = aBF + (size_t)BATCH * NROWS * DDIM;
  float* partials = (float*)(bBF + (size_t)BATCH * MROWS * DDIM);
  float* bloss = partials + (size_t)NSPLIT * BATCH * MROWS;

  const int totRows = BATCH * (NROWS + MROWS);
  norm_cast<<<(totRows + 3) / 4, 256, 0, stream>>>(x1, x2, aBF, bBF);
  maxsim_gemm8<<<BATCH * 8 * NSPLIT, 512, 0, stream>>>(aBF, bBF, partials);
  batch_loss<<<BATCH, 256, 0, stream>>>(partials, y, bloss);
  final_sum<<<1, 64, 0, stream>>>(bloss, out);
}